// Round 2
// baseline (921.323 us; speedup 1.0000x reference)
//
#include <hip/hip_runtime.h>
#include <math.h>

// R1: no bench data yet (2x GPUAcquisitionTimeout). Theory-only restructure:
//  - k4: m-tile 64, O-microtile 4m x 16c (c strided 64) -> VALU-bound not LDS-bound
//  - k5: row-tile 64, thread = 4o x 16r, ds reads wave-uniform broadcasts
// Problem constants (match reference)
constexpr int B_ = 16, N_ = 2048, C_ = 256, K_ = 64;
constexpr float EPS_BN = 1e-5f;

// Workspace layout (float offsets). Total = 4,391,424 floats = 17.6 MB.
constexpr size_t OFF_Q   = 0;                          // B*N*K   q[b][n][o]
constexpr size_t OFF_KT  = OFF_Q   + (size_t)B_*N_*K_; // B*K*N   kT[b][o][n]
constexpr size_t OFF_RM  = OFF_KT  + (size_t)B_*K_*N_; // B*N     row max
constexpr size_t OFF_RSI = OFF_RM  + (size_t)B_*N_;    // B*N     1/rowsum
constexpr size_t OFF_COL = OFF_RSI + (size_t)B_*N_;    // B*N     colsum
constexpr size_t OFF_WTT = OFF_COL + (size_t)B_*N_;    // C*C     Wt^T [c][o]
constexpr size_t OFF_WQT = OFF_WTT + (size_t)C_*C_;    // C*K     Wq^T [c][o]
constexpr size_t OFF_WKT = OFF_WQT + (size_t)C_*K_;    // C*K     Wk^T [c][o]
constexpr size_t OFF_S   = OFF_WKT + (size_t)C_*K_;    // C       bn scale
constexpr size_t OFF_CB  = OFF_S   + (size_t)C_;       // C       bn bias

// ---------------------------------------------------------------------------
// K0: transpose weights + fold BN affine.  bn(t) = s*t + cb with t = Wt@d + bt
__global__ void k0_prep(const float* __restrict__ Wq, const float* __restrict__ Wk,
                        const float* __restrict__ Wt, const float* __restrict__ bt,
                        const float* __restrict__ gamma, const float* __restrict__ beta,
                        const float* __restrict__ mean, const float* __restrict__ var,
                        float* __restrict__ ws) {
  int o = blockIdx.x, c = threadIdx.x;
  ws[OFF_WTT + (size_t)c*C_ + o] = Wt[(size_t)o*C_ + c];
  if (o < K_) {
    ws[OFF_WQT + (size_t)c*K_ + o] = Wq[(size_t)o*C_ + c];
    ws[OFF_WKT + (size_t)c*K_ + o] = Wk[(size_t)o*C_ + c];
  }
  if (o == 0) {
    float s = gamma[c] * rsqrtf(var[c] + EPS_BN);
    ws[OFF_S  + c] = s;
    ws[OFF_CB + c] = s * (bt[c] - mean[c]) + beta[c];
  }
}

// ---------------------------------------------------------------------------
// K1: q[b,n,o] = sum_c x[b,n,c]*Wq[o,c];  kT[b,o,n] = sum_c x[b,n,c]*Wk[o,c]
__global__ __launch_bounds__(256) void k1_qk(const float* __restrict__ x,
                                             float* __restrict__ ws) {
  __shared__ float xs[32][C_];     // 32 KB
  __shared__ float kbuf[K_][33];   // transpose staging for coalesced kT write
  const float* WqT = ws + OFF_WQT;
  const float* WkT = ws + OFF_WKT;
  float* q  = ws + OFF_Q;
  float* kT = ws + OFF_KT;
  int b = blockIdx.x >> 6, nt = blockIdx.x & 63;
  int n0 = nt * 32, tid = threadIdx.x;

  const float4* xg = (const float4*)(x + ((size_t)b*N_ + n0)*C_);
  float4* xsv = (float4*)&xs[0][0];
#pragma unroll
  for (int i = 0; i < 8; i++) xsv[tid + i*256] = xg[tid + i*256];
  __syncthreads();

  int o = tid & 63, rg = tid >> 6;   // rg uniform per wave -> xs reads broadcast
  float aq[8], ak[8];
#pragma unroll
  for (int j = 0; j < 8; j++) { aq[j] = 0.f; ak[j] = 0.f; }
  for (int c = 0; c < C_; c++) {
    float wq = WqT[c*K_ + o];        // coalesced 256B per wave
    float wk = WkT[c*K_ + o];
#pragma unroll
    for (int j = 0; j < 8; j++) {
      float xv = xs[rg*8 + j][c];
      aq[j] = fmaf(xv, wq, aq[j]);
      ak[j] = fmaf(xv, wk, ak[j]);
    }
  }
#pragma unroll
  for (int j = 0; j < 8; j++) {
    int n = n0 + rg*8 + j;
    q[((size_t)b*N_ + n)*K_ + o] = aq[j];  // lanes o consecutive: coalesced
    kbuf[o][rg*8 + j] = ak[j];
  }
  __syncthreads();
#pragma unroll
  for (int i = 0; i < 2; i++) {
    int f = tid + i*256;             // 64 rows x 8 float4
    int oo = f >> 3, m4 = f & 7;
    float4 v = make_float4(kbuf[oo][m4*4], kbuf[oo][m4*4+1],
                           kbuf[oo][m4*4+2], kbuf[oo][m4*4+3]);
    *(float4*)&kT[((size_t)b*K_ + oo)*N_ + n0 + m4*4] = v;
  }
}

// ---------------------------------------------------------------------------
// K3: online-softmax row stats over e[n,m] = q[n]·k[m].
// Block = (b, 64-row tile); thread grid 16x16, 4x4 microtile, m tiled by 64.
__global__ __launch_bounds__(256) void k3_rowstats(float* __restrict__ ws) {
  const float* q  = ws + OFF_Q;
  const float* kT = ws + OFF_KT;
  float* rm  = ws + OFF_RM;
  float* rsi = ws + OFF_RSI;
  __shared__ float qsT[K_][68];       // [c][r]
  __shared__ float ks[K_][64];        // [c][m]
  __shared__ float redM[64][17];
  __shared__ float redS[64][17];
  int b = blockIdx.x >> 5, nt = blockIdx.x & 31;
  int n0 = nt*64, tid = threadIdx.x;
  {
    const float4* qg = (const float4*)(q + ((size_t)b*N_ + n0)*K_);
#pragma unroll
    for (int i = 0; i < 4; i++) {
      int f = tid + i*256;
      int r = f >> 4, c4 = f & 15;
      float4 v = qg[f];
      qsT[c4*4+0][r] = v.x; qsT[c4*4+1][r] = v.y;
      qsT[c4*4+2][r] = v.z; qsT[c4*4+3][r] = v.w;
    }
  }
  int ty = tid >> 4, tx = tid & 15;
  float M[4], S[4];
#pragma unroll
  for (int i = 0; i < 4; i++) { M[i] = -3.0e38f; S[i] = 0.f; }

  for (int mt = 0; mt < N_/64; mt++) {
    __syncthreads();
    const float* kg = kT + (size_t)b*K_*N_ + mt*64;
#pragma unroll
    for (int i = 0; i < 4; i++) {
      int f = tid + i*256;
      int cc = f >> 4, m4 = f & 15;
      *(float4*)&ks[cc][m4*4] = *(const float4*)&kg[(size_t)cc*N_ + m4*4];
    }
    __syncthreads();
    float e[4][4];
#pragma unroll
    for (int i = 0; i < 4; i++)
#pragma unroll
      for (int j = 0; j < 4; j++) e[i][j] = 0.f;
    for (int cc = 0; cc < K_; cc++) {
      float4 qv = *(const float4*)&qsT[cc][ty*4];
      float4 kv = *(const float4*)&ks[cc][tx*4];
      float qa[4] = {qv.x, qv.y, qv.z, qv.w};
      float ka[4] = {kv.x, kv.y, kv.z, kv.w};
#pragma unroll
      for (int i = 0; i < 4; i++)
#pragma unroll
        for (int j = 0; j < 4; j++) e[i][j] = fmaf(qa[i], ka[j], e[i][j]);
    }
#pragma unroll
    for (int i = 0; i < 4; i++) {
      float t0 = fmaxf(fmaxf(e[i][0], e[i][1]), fmaxf(e[i][2], e[i][3]));
      float nM = fmaxf(M[i], t0);
      float sc = __expf(M[i] - nM);
      float s  = __expf(e[i][0]-nM) + __expf(e[i][1]-nM)
               + __expf(e[i][2]-nM) + __expf(e[i][3]-nM);
      S[i] = fmaf(S[i], sc, s);
      M[i] = nM;
    }
  }
#pragma unroll
  for (int i = 0; i < 4; i++) { redM[ty*4+i][tx] = M[i]; redS[ty*4+i][tx] = S[i]; }
  __syncthreads();
  if (tid < 64) {
    float Mg = -3.0e38f;
#pragma unroll
    for (int j = 0; j < 16; j++) Mg = fmaxf(Mg, redM[tid][j]);
    float Sg = 0.f;
#pragma unroll
    for (int j = 0; j < 16; j++) Sg += redS[tid][j] * __expf(redM[tid][j] - Mg);
    rm [(size_t)b*N_ + n0 + tid] = Mg;
    rsi[(size_t)b*N_ + n0 + tid] = 1.0f / Sg;
  }
}

// ---------------------------------------------------------------------------
// K4: O_raw[m,c] = sum_n P[n,m]*x[n,c],  colsum[m] = sum_n P[n,m]
// P[n,m] = exp(q_n·k_m - rm[n]) * rsi[n].
// Block = (b, 64-m tile); n looped in tiles of 32. O_raw -> d_out (scratch).
// P phase: thread = (pn in [0,32), pg in [0,8)) -> 1 n x 8 m.
// O phase: thread = (mog in [0,16), cgr in [0,16)) -> 4 m x 16 c (c strided 64).
constexpr int BM4 = 64;
__global__ __launch_bounds__(256) void k4_ov(const float* __restrict__ x,
                                             float* __restrict__ ws,
                                             float* __restrict__ Oraw) {
  const float* q   = ws + OFF_Q;
  const float* kT  = ws + OFF_KT;
  const float* rm  = ws + OFF_RM;
  const float* rsi = ws + OFF_RSI;
  float* colsum    = ws + OFF_COL;
  __shared__ float ksm[K_][BM4+4];   // [c][m] stride 68: P reads 2-way (free)
  __shared__ float qs[32][K_+4];     // [n][c] stride 68
  __shared__ float xs[32][C_];       // [n][c] 32 KB
  __shared__ float Pl[32][BM4+1];    // [n][m] stride 65: all accesses <=2-way
  __shared__ float rmL[32], rsiL[32];
  int b = blockIdx.x >> 5, mt = blockIdx.x & 31;
  int m0 = mt*BM4, tid = threadIdx.x;

  {  // ksm loaded once per block: 64c x 64m = 1024 float4
    const float* kg = kT + (size_t)b*K_*N_ + m0;
#pragma unroll
    for (int i = 0; i < 4; i++) {
      int f = tid + i*256;
      int cc = f >> 4, m4 = f & 15;
      *(float4*)&ksm[cc][m4*4] = *(const float4*)&kg[(size_t)cc*N_ + m4*4];
    }
  }
  int pn = tid >> 3, pg = tid & 7;
  int mog = tid >> 4, cgr = tid & 15;
  float acc[4][16];
#pragma unroll
  for (int i = 0; i < 4; i++)
#pragma unroll
    for (int j = 0; j < 16; j++) acc[i][j] = 0.f;
  float csum[8];
#pragma unroll
  for (int j = 0; j < 8; j++) csum[j] = 0.f;

  for (int nt = 0; nt < N_/32; nt++) {
    int nn0 = nt*32;
    __syncthreads();
    {  // stage q rows (512 f4) + x rows (2048 f4) + row stats
      const float4* qg = (const float4*)(q + ((size_t)b*N_ + nn0)*K_);
#pragma unroll
      for (int i = 0; i < 2; i++) {
        int f = tid + i*256;
        int r = f >> 4, c4 = f & 15;
        *(float4*)&qs[r][c4*4] = qg[f];
      }
      const float4* xg = (const float4*)(x + ((size_t)b*N_ + nn0)*C_);
      float4* xv = (float4*)&xs[0][0];
#pragma unroll
      for (int i = 0; i < 8; i++) xv[tid + i*256] = xg[tid + i*256];
      if (tid < 32) {
        rmL[tid]  = rm [(size_t)b*N_ + nn0 + tid];
        rsiL[tid] = rsi[(size_t)b*N_ + nn0 + tid];
      }
    }
    __syncthreads();
    // --- P phase: e[n, 8 m] then exp -> Pl
    {
      float e8[8];
#pragma unroll
      for (int j = 0; j < 8; j++) e8[j] = 0.f;
      for (int cc = 0; cc < K_; cc++) {
        float qv = qs[pn][cc];                          // broadcast
        float4 k0 = *(const float4*)&ksm[cc][pg*8];     // 2-way, free
        float4 k1 = *(const float4*)&ksm[cc][pg*8 + 4];
        e8[0] = fmaf(qv, k0.x, e8[0]); e8[1] = fmaf(qv, k0.y, e8[1]);
        e8[2] = fmaf(qv, k0.z, e8[2]); e8[3] = fmaf(qv, k0.w, e8[3]);
        e8[4] = fmaf(qv, k1.x, e8[4]); e8[5] = fmaf(qv, k1.y, e8[5]);
        e8[6] = fmaf(qv, k1.z, e8[6]); e8[7] = fmaf(qv, k1.w, e8[7]);
      }
      float irm = rmL[pn], irs = rsiL[pn];
#pragma unroll
      for (int j = 0; j < 8; j++) {
        float p = __expf(e8[j] - irm) * irs;
        Pl[pn][pg*8 + j] = p;
        csum[j] += p;
      }
    }
    __syncthreads();
    // --- O phase: acc[4 m][16 c] += P[n,m] * x[n,c]
    for (int n = 0; n < 32; n++) {
      float p0 = Pl[n][mog*4 + 0];
      float p1 = Pl[n][mog*4 + 1];
      float p2 = Pl[n][mog*4 + 2];
      float p3 = Pl[n][mog*4 + 3];
#pragma unroll
      for (int k = 0; k < 4; k++) {
        float4 xv4 = *(const float4*)&xs[n][cgr*4 + k*64];  // 2-way, free
        acc[0][k*4+0] = fmaf(p0, xv4.x, acc[0][k*4+0]);
        acc[0][k*4+1] = fmaf(p0, xv4.y, acc[0][k*4+1]);
        acc[0][k*4+2] = fmaf(p0, xv4.z, acc[0][k*4+2]);
        acc[0][k*4+3] = fmaf(p0, xv4.w, acc[0][k*4+3]);
        acc[1][k*4+0] = fmaf(p1, xv4.x, acc[1][k*4+0]);
        acc[1][k*4+1] = fmaf(p1, xv4.y, acc[1][k*4+1]);
        acc[1][k*4+2] = fmaf(p1, xv4.z, acc[1][k*4+2]);
        acc[1][k*4+3] = fmaf(p1, xv4.w, acc[1][k*4+3]);
        acc[2][k*4+0] = fmaf(p2, xv4.x, acc[2][k*4+0]);
        acc[2][k*4+1] = fmaf(p2, xv4.y, acc[2][k*4+1]);
        acc[2][k*4+2] = fmaf(p2, xv4.z, acc[2][k*4+2]);
        acc[2][k*4+3] = fmaf(p2, xv4.w, acc[2][k*4+3]);
        acc[3][k*4+0] = fmaf(p3, xv4.x, acc[3][k*4+0]);
        acc[3][k*4+1] = fmaf(p3, xv4.y, acc[3][k*4+1]);
        acc[3][k*4+2] = fmaf(p3, xv4.z, acc[3][k*4+2]);
        acc[3][k*4+3] = fmaf(p3, xv4.w, acc[3][k*4+3]);
      }
    }
  }
#pragma unroll
  for (int ml = 0; ml < 4; ml++)
#pragma unroll
    for (int k = 0; k < 4; k++) {
      float4 v = make_float4(acc[ml][k*4], acc[ml][k*4+1],
                             acc[ml][k*4+2], acc[ml][k*4+3]);
      *(float4*)&Oraw[((size_t)b*N_ + m0 + mog*4 + ml)*C_ + cgr*4 + k*64] = v;
    }
  // colsum reduce: reuse Pl as scratch (csum[j] holds sum over this thread's n)
  __syncthreads();
#pragma unroll
  for (int j = 0; j < 8; j++) Pl[pn][pg*8 + j] = csum[j];
  __syncthreads();
  if (tid < BM4) {
    float s = 0.f;
    for (int r = 0; r < 32; r++) s += Pl[r][tid];
    colsum[(size_t)b*N_ + m0 + tid] = s;
  }
}

// ---------------------------------------------------------------------------
// K5: d = x - O_raw/(1e-6+colsum); out = x + relu(s*(WtT·d) + cb). In-place.
// Block = (b, 64-row tile). Thread = (og in [0,64) -> 4 o, rg in [0,4) -> 16 r).
// ds reads are wave-uniform broadcasts; WtT reads coalesced 1KB/wave from L2.
constexpr int BR5 = 64;
__global__ __launch_bounds__(256) void k5_epi(const float* __restrict__ x,
                                              float* __restrict__ ws,
                                              float* __restrict__ out) {
  const float* WtT  = ws + OFF_WTT;
  const float* Sarr = ws + OFF_S;
  const float* Carr = ws + OFF_CB;
  const float* colsum = ws + OFF_COL;
  __shared__ float ds[BR5][C_];   // 64 KB
  __shared__ float icsL[BR5];
  int b = blockIdx.x >> 5, nt = blockIdx.x & 31;
  int n0 = nt*BR5, tid = threadIdx.x;
  if (tid < BR5) icsL[tid] = 1.0f / (1e-6f + colsum[(size_t)b*N_ + n0 + tid]);
  __syncthreads();
  const float4* xg = (const float4*)(x   + ((size_t)b*N_ + n0)*C_);
  const float4* og = (const float4*)(out + ((size_t)b*N_ + n0)*C_);
#pragma unroll
  for (int i = 0; i < 16; i++) {
    int f = tid + i*256;
    int r = f >> 6;
    float4 xv = xg[f];
    float4 ov = og[f];
    float ic = icsL[r];
    float4 d;
    d.x = xv.x - ov.x*ic; d.y = xv.y - ov.y*ic;
    d.z = xv.z - ov.z*ic; d.w = xv.w - ov.w*ic;
    *(float4*)&ds[r][(f & 63)*4] = d;
  }
  __syncthreads();   // all O_raw reads done before any overwrite below
  int og_ = tid & 63, rg = tid >> 6;   // rg uniform per wave
  float acc[16][4];
#pragma unroll
  for (int r = 0; r < 16; r++)
#pragma unroll
    for (int j = 0; j < 4; j++) acc[r][j] = 0.f;
  for (int cc = 0; cc < C_; cc++) {
    float4 w = *(const float4*)&WtT[(size_t)cc*C_ + og_*4];  // coalesced
#pragma unroll
    for (int r = 0; r < 16; r++) {
      float dv = ds[rg*16 + r][cc];    // wave-uniform broadcast
      acc[r][0] = fmaf(dv, w.x, acc[r][0]);
      acc[r][1] = fmaf(dv, w.y, acc[r][1]);
      acc[r][2] = fmaf(dv, w.z, acc[r][2]);
      acc[r][3] = fmaf(dv, w.w, acc[r][3]);
    }
  }
  float4 s4 = *(const float4*)&Sarr[og_*4];
  float4 c4 = *(const float4*)&Carr[og_*4];
#pragma unroll
  for (int r = 0; r < 16; r++) {
    size_t row = (size_t)b*N_ + n0 + rg*16 + r;
    float4 xv = *(const float4*)&x[row*C_ + og_*4];
    float4 o;
    float bn0 = fmaf(s4.x, acc[r][0], c4.x);
    float bn1 = fmaf(s4.y, acc[r][1], c4.y);
    float bn2 = fmaf(s4.z, acc[r][2], c4.z);
    float bn3 = fmaf(s4.w, acc[r][3], c4.w);
    o.x = xv.x + (bn0 > 0.f ? bn0 : 0.f);
    o.y = xv.y + (bn1 > 0.f ? bn1 : 0.f);
    o.z = xv.z + (bn2 > 0.f ? bn2 : 0.f);
    o.w = xv.w + (bn3 > 0.f ? bn3 : 0.f);
    *(float4*)&out[row*C_ + og_*4] = o;
  }
}

// ---------------------------------------------------------------------------
extern "C" void kernel_launch(void* const* d_in, const int* in_sizes, int n_in,
                              void* d_out, int out_size, void* d_ws, size_t ws_size,
                              hipStream_t stream) {
  (void)in_sizes; (void)n_in; (void)out_size; (void)ws_size;
  const float* x     = (const float*)d_in[0];
  const float* Wq    = (const float*)d_in[1];
  const float* Wk    = (const float*)d_in[2];
  // d_in[3] (Wv) / d_in[4] (bv): dead in reference forward — skipped.
  const float* Wt    = (const float*)d_in[5];
  const float* bt    = (const float*)d_in[6];
  const float* gamma = (const float*)d_in[7];
  const float* beta  = (const float*)d_in[8];
  const float* mean  = (const float*)d_in[9];
  const float* var   = (const float*)d_in[10];
  float* ws  = (float*)d_ws;
  float* out = (float*)d_out;

  k0_prep     <<<C_,            C_,  0, stream>>>(Wq, Wk, Wt, bt, gamma, beta, mean, var, ws);
  k1_qk       <<<B_*(N_/32),    256, 0, stream>>>(x, ws);
  k3_rowstats <<<B_*(N_/64),    256, 0, stream>>>(ws);
  k4_ov       <<<B_*(N_/64),    256, 0, stream>>>(x, ws, out);
  k5_epi      <<<B_*(N_/64),    256, 0, stream>>>(x, ws, out);
}

// Round 5
// 451.647 us; speedup vs baseline: 2.0399x; 2.0399x over previous
//
#include <hip/hip_runtime.h>
#include <math.h>
#include <stdint.h>

// R5 = R3/R4 resubmit (GPU never acquired; design desk-audited twice).
// bf16-MFMA rewrite of the two N*N GEMM passes; split-bf16 hi/lo operands
// (3 MFMAs per product) keep added error ~1e-6 relative. fp32 k1/k5 from R2.
constexpr int B_ = 16, N_ = 2048, C_ = 256, K_ = 64;
constexpr float EPS_BN = 1e-5f;

typedef __attribute__((ext_vector_type(8))) short short8;
typedef __attribute__((ext_vector_type(16))) float f32x16;

#define MFMA32(A, Bf, Cc) __builtin_amdgcn_mfma_f32_32x32x16_bf16(A, Bf, Cc, 0, 0, 0)

// ---- workspace byte offsets (total ~48.6 MiB) ----
constexpr size_t SZ_QK  = (size_t)B_*N_*K_*2;          // 4 MiB per array
constexpr size_t WSB_QH = 0;
constexpr size_t WSB_QL = WSB_QH + SZ_QK;
constexpr size_t WSB_KH = WSB_QL + SZ_QK;
constexpr size_t WSB_KL = WSB_KH + SZ_QK;
constexpr size_t WSB_Z  = WSB_KL + SZ_QK;              // B*N f32
constexpr size_t WSB_CS = WSB_Z  + (size_t)B_*N_*4;    // B*N f32 colsum
constexpr size_t WSB_WQT= WSB_CS + (size_t)B_*N_*4;    // C*K f32
constexpr size_t WSB_WKT= WSB_WQT+ (size_t)C_*K_*4;
constexpr size_t WSB_WTT= WSB_WKT+ (size_t)C_*K_*4;    // C*C f32
constexpr size_t WSB_S  = WSB_WTT+ (size_t)C_*C_*4;
constexpr size_t WSB_CB = WSB_S  + (size_t)C_*4;
constexpr size_t WSB_O  = (WSB_CB + (size_t)C_*4 + 255) & ~(size_t)255;  // B*N*C f32

// xT (split bf16, MFMA-B-fragment tile order) lives in d_out: hi at 0, lo at:
constexpr size_t XT_LO = (size_t)B_*N_*C_*2;           // 16.78 MB each half

__device__ inline unsigned short bf16_rne(float f) {
  uint32_t u = __float_as_uint(f);
  uint32_t r = u + 0x7FFFu + ((u >> 16) & 1u);
  return (unsigned short)(r >> 16);
}

#define GLOAD_LDS16(g, l) __builtin_amdgcn_global_load_lds( \
    (const __attribute__((address_space(1))) unsigned int*)(g), \
    (__attribute__((address_space(3))) unsigned int*)(l), 16, 0, 0)

// ---------------------------------------------------------------------------
// K0: transpose weights + fold BN affine
__global__ void k0_prep(const float* __restrict__ Wq, const float* __restrict__ Wk,
                        const float* __restrict__ Wt, const float* __restrict__ bt,
                        const float* __restrict__ gamma, const float* __restrict__ beta,
                        const float* __restrict__ mean, const float* __restrict__ var,
                        char* __restrict__ ws) {
  int o = blockIdx.x, c = threadIdx.x;
  ((float*)(ws + WSB_WTT))[(size_t)c*C_ + o] = Wt[(size_t)o*C_ + c];
  if (o < K_) {
    ((float*)(ws + WSB_WQT))[(size_t)c*K_ + o] = Wq[(size_t)o*C_ + c];
    ((float*)(ws + WSB_WKT))[(size_t)c*K_ + o] = Wk[(size_t)o*C_ + c];
  }
  if (o == 0) {
    float s = gamma[c] * rsqrtf(var[c] + EPS_BN);
    ((float*)(ws + WSB_S))[c]  = s;
    ((float*)(ws + WSB_CB))[c] = s * (bt[c] - mean[c]) + beta[c];
  }
}

// ---------------------------------------------------------------------------
// K1: q/k projections -> split bf16 [b][n][64]; x -> split bf16 xT tiles in
// d_out, tile layout [b][nt][nchunk 4][c 256][8 n] (16B words) so k4 can
// global_load_lds linearly and ds_read_b128 conflict-free.
__global__ __launch_bounds__(256) void k1_qk(const float* __restrict__ x,
                                             char* __restrict__ ws,
                                             char* __restrict__ xtbuf) {
  __shared__ float xs[32][260];
  const float* WqT = (const float*)(ws + WSB_WQT);
  const float* WkT = (const float*)(ws + WSB_WKT);
  unsigned short* qh = (unsigned short*)(ws + WSB_QH);
  unsigned short* ql = (unsigned short*)(ws + WSB_QL);
  unsigned short* kh = (unsigned short*)(ws + WSB_KH);
  unsigned short* kl = (unsigned short*)(ws + WSB_KL);
  int b = blockIdx.x >> 6, nt = blockIdx.x & 63;
  int n0 = nt * 32, tid = threadIdx.x;

  const float4* xg = (const float4*)(x + ((size_t)b*N_ + n0)*C_);
#pragma unroll
  for (int i = 0; i < 8; i++) {
    int f = tid + i*256;
    int r = f >> 6, c4 = f & 63;
    *(float4*)&xs[r][c4*4] = xg[f];
  }
  __syncthreads();

  int o = tid & 63, rg = tid >> 6;
  float aq[8], ak[8];
#pragma unroll
  for (int j = 0; j < 8; j++) { aq[j] = 0.f; ak[j] = 0.f; }
  for (int c = 0; c < C_; c++) {
    float wq = WqT[c*K_ + o];
    float wk = WkT[c*K_ + o];
#pragma unroll
    for (int j = 0; j < 8; j++) {
      float xv = xs[rg*8 + j][c];
      aq[j] = fmaf(xv, wq, aq[j]);
      ak[j] = fmaf(xv, wk, ak[j]);
    }
  }
#pragma unroll
  for (int j = 0; j < 8; j++) {
    int n = n0 + rg*8 + j;
    size_t base = ((size_t)b*N_ + n)*K_ + o;
    float q = aq[j];
    uint32_t qb = __float_as_uint(q) & 0xFFFF0000u;
    qh[base] = (unsigned short)(qb >> 16);
    ql[base] = bf16_rne(q - __uint_as_float(qb));
    float k = ak[j];
    uint32_t kb = __float_as_uint(k) & 0xFFFF0000u;
    kh[base] = (unsigned short)(kb >> 16);
    kl[base] = bf16_rne(k - __uint_as_float(kb));
  }
  // xT split tiles: thread = c; word j holds n = n0 + nc*8 + j
#pragma unroll
  for (int nc = 0; nc < 4; nc++) {
    uint32_t hw[4], lw[4];
#pragma unroll
    for (int jj = 0; jj < 4; jj++) {
      float a  = xs[nc*8 + jj*2    ][tid];
      float bv = xs[nc*8 + jj*2 + 1][tid];
      uint32_t ab = __float_as_uint(a)  & 0xFFFF0000u;
      uint32_t bb = __float_as_uint(bv) & 0xFFFF0000u;
      hw[jj] = (ab >> 16) | bb;
      float alo = a  - __uint_as_float(ab);
      float blo = bv - __uint_as_float(bb);
      lw[jj] = (uint32_t)bf16_rne(alo) | ((uint32_t)bf16_rne(blo) << 16);
    }
    size_t toff = ((size_t)(b*64 + nt))*16384 + ((size_t)nc*256 + tid)*16;
    *(uint4*)(xtbuf + toff)         = make_uint4(hw[0], hw[1], hw[2], hw[3]);
    *(uint4*)(xtbuf + XT_LO + toff) = make_uint4(lw[0], lw[1], lw[2], lw[3]);
  }
}

// ---------------------------------------------------------------------------
// K3: Z[n] = rowmax_m(e) + ln(rowsum exp). E-tiles via mfma(A=k rows m,
// B=q cols n): D col = n (lane-fixed) -> lane-local online stats over m.
__global__ __launch_bounds__(256) void k3_stats(char* __restrict__ ws) {
  int b = blockIdx.x >> 4, nb = blockIdx.x & 15;
  int tid = threadIdx.x, wave = tid >> 6, l = tid & 63;
  int lo5 = l & 31, hi5 = l >> 5;
  int n = nb*128 + wave*32 + lo5;

  short8 qhf[4], qlf[4];
  size_t qoff = ((size_t)b*N_ + n)*K_;
#pragma unroll
  for (int cs = 0; cs < 4; cs++) {
    qhf[cs] = *(const short8*)(ws + WSB_QH + (qoff + cs*16 + hi5*8)*2);
    qlf[cs] = *(const short8*)(ws + WSB_QL + (qoff + cs*16 + hi5*8)*2);
  }
  float M = -3.0e38f, S = 0.f;
  for (int mt = 0; mt < 64; mt++) {
    int mm0 = mt*32;
    size_t koff = ((size_t)b*N_ + mm0 + lo5)*K_;
    short8 khf[4], klf[4];
#pragma unroll
    for (int cs = 0; cs < 4; cs++) {
      khf[cs] = *(const short8*)(ws + WSB_KH + (koff + cs*16 + hi5*8)*2);
      klf[cs] = *(const short8*)(ws + WSB_KL + (koff + cs*16 + hi5*8)*2);
    }
    f32x16 E = {0.f};
#pragma unroll
    for (int cs = 0; cs < 4; cs++) {
      E = MFMA32(khf[cs], qhf[cs], E);
      E = MFMA32(khf[cs], qlf[cs], E);
      E = MFMA32(klf[cs], qhf[cs], E);
    }
    float tmax = E[0];
#pragma unroll
    for (int r = 1; r < 16; r++) tmax = fmaxf(tmax, E[r]);
    float nM = fmaxf(M, tmax);
    float sc = __expf(M - nM);
    float ss = 0.f;
#pragma unroll
    for (int r = 0; r < 16; r++) ss += __expf(E[r] - nM);
    S = fmaf(S, sc, ss);
    M = nM;
  }
  float Mo = __shfl_xor(M, 32, 64);
  float So = __shfl_xor(S, 32, 64);
  float Mg = fmaxf(M, Mo);
  float Sg = S*__expf(M - Mg) + So*__expf(Mo - Mg);
  if (hi5 == 0)
    ((float*)(ws + WSB_Z))[(size_t)b*N_ + n] = Mg + __logf(Sg);
}

// ---------------------------------------------------------------------------
// K4: O[m,c] = sum_n exp(e[n,m]-Z[n]) * x[n,c]; colsum[m] = sum_n P.
// Block = (b, 64-m); 4 waves: wave = (msub = w>>1)*32 m x (c0 = (w&1)*128).
// Per n-tile(32): E = mfma(q, k) [D: col=m], P=exp(E-Z), T12 relayout
// (cvt_pk + permlane32_swap) -> PV mfma with LDS-staged xT B-frags.
__global__ __launch_bounds__(256) void k4_ov(char* __restrict__ ws,
                                             const char* __restrict__ xtbuf) {
  __shared__ __align__(16) char xtile[32768];   // hi 16KB | lo 16KB
  __shared__ float zs[32];
  int b = blockIdx.x >> 5, mblk = blockIdx.x & 31;
  int m0 = mblk*64;
  int tid = threadIdx.x, wave = tid >> 6, l = tid & 63;
  int lo5 = l & 31, hi5 = l >> 5;
  int msub = wave >> 1, c0 = (wave & 1)*128;
  int mg = m0 + msub*32 + lo5;

  short8 khf[4], klf[4];                         // loop-invariant B-frags (cols m)
  size_t koff = ((size_t)b*N_ + mg)*K_;
#pragma unroll
  for (int cs = 0; cs < 4; cs++) {
    khf[cs] = *(const short8*)(ws + WSB_KH + (koff + cs*16 + hi5*8)*2);
    klf[cs] = *(const short8*)(ws + WSB_KL + (koff + cs*16 + hi5*8)*2);
  }
  f32x16 accO[4];
#pragma unroll
  for (int ct = 0; ct < 4; ct++) accO[ct] = (f32x16){0.f};
  float csum = 0.f;
  const float* Zp = (const float*)(ws + WSB_Z);

  for (int nt = 0; nt < 64; nt++) {
    int nn0 = nt*32;
    __syncthreads();
    size_t src = (size_t)(b*64 + nt)*16384 + (size_t)tid*16;
#pragma unroll
    for (int i = 0; i < 4; i++)
      GLOAD_LDS16(xtbuf + src + (size_t)i*4096, xtile + tid*16 + i*4096);
#pragma unroll
    for (int i = 0; i < 4; i++)
      GLOAD_LDS16(xtbuf + XT_LO + src + (size_t)i*4096, xtile + 16384 + tid*16 + i*4096);
    if (tid < 32) zs[tid] = Zp[(size_t)b*N_ + nn0 + tid];
    // q A-frags (rows n) direct from L2
    short8 qaf[4], qalf[4];
    size_t qoff = ((size_t)b*N_ + nn0 + lo5)*K_;
#pragma unroll
    for (int cs = 0; cs < 4; cs++) {
      qaf[cs]  = *(const short8*)(ws + WSB_QH + (qoff + cs*16 + hi5*8)*2);
      qalf[cs] = *(const short8*)(ws + WSB_QL + (qoff + cs*16 + hi5*8)*2);
    }
    __syncthreads();
    // QK^T: E[n(reg-rows)][m(col=lane&31)]
    f32x16 E = {0.f};
#pragma unroll
    for (int cs = 0; cs < 4; cs++) {
      E = MFMA32(qaf[cs],  khf[cs], E);
      E = MFMA32(qaf[cs],  klf[cs], E);
      E = MFMA32(qalf[cs], khf[cs], E);
    }
    // P = exp(E - Z[n]); split hi/lo
    float ph[16], pl[16];
#pragma unroll
    for (int r = 0; r < 16; r++) {
      int nr = (r & 3) + 8*(r >> 2) + 4*hi5;
      float p = __expf(E[r] - zs[nr]);
      csum += p;
      uint32_t pb = __float_as_uint(p) & 0xFFFF0000u;
      ph[r] = __uint_as_float(pb);
      pl[r] = p - ph[r];
    }
    // pack + permlane32_swap -> PV A-frags (row=m=lane&31, k=n)
    uint32_t Wh[8], Wl[8];
#pragma unroll
    for (int i = 0; i < 8; i++) {
      Wh[i] = (__float_as_uint(ph[2*i]) >> 16) | (__float_as_uint(ph[2*i+1]) & 0xFFFF0000u);
      uint32_t w;
      asm("v_cvt_pk_bf16_f32 %0, %1, %2" : "=v"(w) : "v"(pl[2*i]), "v"(pl[2*i+1]));
      Wl[i] = w;
    }
    short8 pha[2], pla[2];
#pragma unroll
    for (int s = 0; s < 2; s++) {
      uint32_t a0 = Wh[s*4+0], b0 = Wh[s*4+2];
      uint32_t a1 = Wh[s*4+1], b1 = Wh[s*4+3];
      asm("v_permlane32_swap_b32 %0, %1" : "+v"(a0), "+v"(b0));
      asm("v_permlane32_swap_b32 %0, %1" : "+v"(a1), "+v"(b1));
      union { uint32_t w[4]; short8 s8; } uh;
      uh.w[0] = a0; uh.w[1] = a1; uh.w[2] = b0; uh.w[3] = b1;
      pha[s] = uh.s8;
      uint32_t c0w = Wl[s*4+0], d0 = Wl[s*4+2];
      uint32_t c1w = Wl[s*4+1], d1 = Wl[s*4+3];
      asm("v_permlane32_swap_b32 %0, %1" : "+v"(c0w), "+v"(d0));
      asm("v_permlane32_swap_b32 %0, %1" : "+v"(c1w), "+v"(d1));
      union { uint32_t w[4]; short8 s8; } ul;
      ul.w[0] = c0w; ul.w[1] = c1w; ul.w[2] = d0; ul.w[3] = d1;
      pla[s] = ul.s8;
    }
    // PV: accO[ct] += P^T * x  (B-frags from swizzle-free pre-tiled LDS)
#pragma unroll
    for (int ct = 0; ct < 4; ct++) {
      int cc = c0 + ct*32 + lo5;
      short8 bh[2], bl[2];
#pragma unroll
      for (int ns = 0; ns < 2; ns++) {
        size_t off = ((size_t)((ns*2 + hi5)*256 + cc))*16;
        bh[ns] = *(const short8*)(xtile + off);
        bl[ns] = *(const short8*)(xtile + 16384 + off);
      }
#pragma unroll
      for (int ns = 0; ns < 2; ns++) {
        accO[ct] = MFMA32(pha[ns], bh[ns], accO[ct]);
        accO[ct] = MFMA32(pha[ns], bl[ns], accO[ct]);
        accO[ct] = MFMA32(pla[ns], bh[ns], accO[ct]);
      }
    }
  }
  csum += __shfl_xor(csum, 32, 64);
  if ((wave & 1) == 0 && hi5 == 0)
    ((float*)(ws + WSB_CS))[(size_t)b*N_ + mg] = csum;
  float* Op = (float*)(ws + WSB_O);
#pragma unroll
  for (int ct = 0; ct < 4; ct++) {
#pragma unroll
    for (int r = 0; r < 16; r++) {
      int mm = m0 + msub*32 + (r & 3) + 8*(r >> 2) + 4*hi5;
      int cc = c0 + ct*32 + lo5;
      Op[((size_t)b*N_ + mm)*C_ + cc] = accO[ct][r];
    }
  }
}

// ---------------------------------------------------------------------------
// K5: d = x - O/(1e-6+colsum); out = x + relu(s*(WtT.d) + cb)
constexpr int BR5 = 64;
__global__ __launch_bounds__(256) void k5_epi(const float* __restrict__ x,
                                              char* __restrict__ ws,
                                              float* __restrict__ out) {
  const float* WtT  = (const float*)(ws + WSB_WTT);
  const float* Sarr = (const float*)(ws + WSB_S);
  const float* Carr = (const float*)(ws + WSB_CB);
  const float* colsum = (const float*)(ws + WSB_CS);
  const float* Oraw = (const float*)(ws + WSB_O);
  __shared__ float ds[BR5][C_];
  __shared__ float icsL[BR5];
  int b = blockIdx.x >> 5, nt = blockIdx.x & 31;
  int n0 = nt*BR5, tid = threadIdx.x;
  if (tid < BR5) icsL[tid] = 1.0f / (1e-6f + colsum[(size_t)b*N_ + n0 + tid]);
  __syncthreads();
  const float4* xg = (const float4*)(x    + ((size_t)b*N_ + n0)*C_);
  const float4* og = (const float4*)(Oraw + ((size_t)b*N_ + n0)*C_);
#pragma unroll
  for (int i = 0; i < 16; i++) {
    int f = tid + i*256;
    int r = f >> 6;
    float4 xv = xg[f];
    float4 ov = og[f];
    float ic = icsL[r];
    float4 d;
    d.x = xv.x - ov.x*ic; d.y = xv.y - ov.y*ic;
    d.z = xv.z - ov.z*ic; d.w = xv.w - ov.w*ic;
    *(float4*)&ds[r][(f & 63)*4] = d;
  }
  __syncthreads();
  int og_ = tid & 63, rg = tid >> 6;
  float acc[16][4];
#pragma unroll
  for (int r = 0; r < 16; r++)
#pragma unroll
    for (int j = 0; j < 4; j++) acc[r][j] = 0.f;
  for (int cc = 0; cc < C_; cc++) {
    float4 w = *(const float4*)&WtT[(size_t)cc*C_ + og_*4];
#pragma unroll
    for (int r = 0; r < 16; r++) {
      float dv = ds[rg*16 + r][cc];
      acc[r][0] = fmaf(dv, w.x, acc[r][0]);
      acc[r][1] = fmaf(dv, w.y, acc[r][1]);
      acc[r][2] = fmaf(dv, w.z, acc[r][2]);
      acc[r][3] = fmaf(dv, w.w, acc[r][3]);
    }
  }
  float4 s4 = *(const float4*)&Sarr[og_*4];
  float4 c4 = *(const float4*)&Carr[og_*4];
#pragma unroll
  for (int r = 0; r < 16; r++) {
    size_t row = (size_t)b*N_ + n0 + rg*16 + r;
    float4 xv = *(const float4*)&x[row*C_ + og_*4];
    float4 o;
    float bn0 = fmaf(s4.x, acc[r][0], c4.x);
    float bn1 = fmaf(s4.y, acc[r][1], c4.y);
    float bn2 = fmaf(s4.z, acc[r][2], c4.z);
    float bn3 = fmaf(s4.w, acc[r][3], c4.w);
    o.x = xv.x + (bn0 > 0.f ? bn0 : 0.f);
    o.y = xv.y + (bn1 > 0.f ? bn1 : 0.f);
    o.z = xv.z + (bn2 > 0.f ? bn2 : 0.f);
    o.w = xv.w + (bn3 > 0.f ? bn3 : 0.f);
    *(float4*)&out[row*C_ + og_*4] = o;
  }
}

// ---------------------------------------------------------------------------
extern "C" void kernel_launch(void* const* d_in, const int* in_sizes, int n_in,
                              void* d_out, int out_size, void* d_ws, size_t ws_size,
                              hipStream_t stream) {
  (void)in_sizes; (void)n_in; (void)out_size; (void)ws_size;
  const float* x     = (const float*)d_in[0];
  const float* Wq    = (const float*)d_in[1];
  const float* Wk    = (const float*)d_in[2];
  // d_in[3] (Wv) / d_in[4] (bv): dead in reference forward.
  const float* Wt    = (const float*)d_in[5];
  const float* bt    = (const float*)d_in[6];
  const float* gamma = (const float*)d_in[7];
  const float* beta  = (const float*)d_in[8];
  const float* mean  = (const float*)d_in[9];
  const float* var   = (const float*)d_in[10];
  char* ws = (char*)d_ws;
  char* xt = (char*)d_out;        // xT split tiles live in d_out until k5
  float* out = (float*)d_out;

  k0_prep <<<C_,        C_,  0, stream>>>(Wq, Wk, Wt, bt, gamma, beta, mean, var, ws);
  k1_qk   <<<B_*64,     256, 0, stream>>>(x, ws, xt);
  k3_stats<<<B_*16,     256, 0, stream>>>(ws);
  k4_ov   <<<B_*32,     256, 0, stream>>>(ws, xt);
  k5_epi  <<<B_*32,     256, 0, stream>>>(x, ws, out);
}

// Round 6
// 413.827 us; speedup vs baseline: 2.2263x; 1.0914x over previous
//
#include <hip/hip_runtime.h>
#include <math.h>
#include <stdint.h>

// R6: (a) k4 double-buffered staging (T3-min: stage(nt+1) before compute(nt),
// 1 barrier/tile) + q-frag prefetch; (b) k5 fused into k4 epilogue via
// split-bf16 MFMA (d -> swizzled LDS, Wt split-bf16 from L2), killing the
// separate fp32 GEMM kernel and ~400 MB of O/x HBM round-trip.
constexpr int B_ = 16, N_ = 2048, C_ = 256, K_ = 64;
constexpr float EPS_BN = 1e-5f;

typedef __attribute__((ext_vector_type(8))) short short8;
typedef __attribute__((ext_vector_type(16))) float f32x16;

#define MFMA32(A, Bf, Cc) __builtin_amdgcn_mfma_f32_32x32x16_bf16(A, Bf, Cc, 0, 0, 0)

// ---- workspace byte offsets (total ~51 MiB) ----
constexpr size_t SZ_QK  = (size_t)B_*N_*K_*2;            // 4 MiB each
constexpr size_t WSB_QH = 0;
constexpr size_t WSB_QL = WSB_QH + SZ_QK;
constexpr size_t WSB_KH = WSB_QL + SZ_QK;
constexpr size_t WSB_KL = WSB_KH + SZ_QK;
constexpr size_t WSB_Z  = WSB_KL + SZ_QK;                // B*N f32
constexpr size_t WSB_WQT= WSB_Z  + (size_t)B_*N_*4;      // C*K f32
constexpr size_t WSB_WKT= WSB_WQT+ (size_t)C_*K_*4;
constexpr size_t WSB_S  = WSB_WKT+ (size_t)C_*K_*4;      // C f32 bn scale
constexpr size_t WSB_CB = WSB_S  + (size_t)C_*4;         // C f32 bn bias
constexpr size_t WSB_WBH= WSB_CB + (size_t)C_*4;         // C*C bf16 Wt hi [o][c]
constexpr size_t WSB_WBL= WSB_WBH+ (size_t)C_*C_*2;      // C*C bf16 Wt lo
constexpr size_t WSB_XT = (WSB_WBL + (size_t)C_*C_*2 + 255) & ~(size_t)255;
constexpr size_t XT_HALF= (size_t)B_*N_*C_*2;            // 16.78 MB (hi), lo at +XT_HALF

__device__ inline unsigned short bf16_rne(float f) {
  uint32_t u = __float_as_uint(f);
  uint32_t r = u + 0x7FFFu + ((u >> 16) & 1u);
  return (unsigned short)(r >> 16);
}

#define GLOAD_LDS16(g, l) __builtin_amdgcn_global_load_lds( \
    (const __attribute__((address_space(1))) unsigned int*)(g), \
    (__attribute__((address_space(3))) unsigned int*)(l), 16, 0, 0)

// ---------------------------------------------------------------------------
// K0: transpose weights, split Wt to bf16 hi/lo [o][c], fold BN affine
__global__ void k0_prep(const float* __restrict__ Wq, const float* __restrict__ Wk,
                        const float* __restrict__ Wt, const float* __restrict__ bt,
                        const float* __restrict__ gamma, const float* __restrict__ beta,
                        const float* __restrict__ mean, const float* __restrict__ var,
                        char* __restrict__ ws) {
  int o = blockIdx.x, c = threadIdx.x;
  {
    float w = Wt[(size_t)o*C_ + c];
    uint32_t wb = __float_as_uint(w) & 0xFFFF0000u;
    ((unsigned short*)(ws + WSB_WBH))[(size_t)o*C_ + c] = (unsigned short)(wb >> 16);
    ((unsigned short*)(ws + WSB_WBL))[(size_t)o*C_ + c] = bf16_rne(w - __uint_as_float(wb));
  }
  if (o < K_) {
    ((float*)(ws + WSB_WQT))[(size_t)c*K_ + o] = Wq[(size_t)o*C_ + c];
    ((float*)(ws + WSB_WKT))[(size_t)c*K_ + o] = Wk[(size_t)o*C_ + c];
  }
  if (o == 0) {
    float s = gamma[c] * rsqrtf(var[c] + EPS_BN);
    ((float*)(ws + WSB_S))[c]  = s;
    ((float*)(ws + WSB_CB))[c] = s * (bt[c] - mean[c]) + beta[c];
  }
}

// ---------------------------------------------------------------------------
// K1: q/k projections -> split bf16 [b][n][64]; x -> split bf16 xT tiles in
// ws (layout [b][nt][nchunk 4][c 256][8 n] 16B words) for k4 global_load_lds.
__global__ __launch_bounds__(256) void k1_qk(const float* __restrict__ x,
                                             char* __restrict__ ws,
                                             char* __restrict__ xtbuf) {
  __shared__ float xs[32][260];
  const float* WqT = (const float*)(ws + WSB_WQT);
  const float* WkT = (const float*)(ws + WSB_WKT);
  unsigned short* qh = (unsigned short*)(ws + WSB_QH);
  unsigned short* ql = (unsigned short*)(ws + WSB_QL);
  unsigned short* kh = (unsigned short*)(ws + WSB_KH);
  unsigned short* kl = (unsigned short*)(ws + WSB_KL);
  int b = blockIdx.x >> 6, nt = blockIdx.x & 63;
  int n0 = nt * 32, tid = threadIdx.x;

  const float4* xg = (const float4*)(x + ((size_t)b*N_ + n0)*C_);
#pragma unroll
  for (int i = 0; i < 8; i++) {
    int f = tid + i*256;
    int r = f >> 6, c4 = f & 63;
    *(float4*)&xs[r][c4*4] = xg[f];
  }
  __syncthreads();

  int o = tid & 63, rg = tid >> 6;
  float aq[8], ak[8];
#pragma unroll
  for (int j = 0; j < 8; j++) { aq[j] = 0.f; ak[j] = 0.f; }
  for (int c = 0; c < C_; c++) {
    float wq = WqT[c*K_ + o];
    float wk = WkT[c*K_ + o];
#pragma unroll
    for (int j = 0; j < 8; j++) {
      float xv = xs[rg*8 + j][c];
      aq[j] = fmaf(xv, wq, aq[j]);
      ak[j] = fmaf(xv, wk, ak[j]);
    }
  }
#pragma unroll
  for (int j = 0; j < 8; j++) {
    int n = n0 + rg*8 + j;
    size_t base = ((size_t)b*N_ + n)*K_ + o;
    float q = aq[j];
    uint32_t qb = __float_as_uint(q) & 0xFFFF0000u;
    qh[base] = (unsigned short)(qb >> 16);
    ql[base] = bf16_rne(q - __uint_as_float(qb));
    float k = ak[j];
    uint32_t kb = __float_as_uint(k) & 0xFFFF0000u;
    kh[base] = (unsigned short)(kb >> 16);
    kl[base] = bf16_rne(k - __uint_as_float(kb));
  }
#pragma unroll
  for (int nc = 0; nc < 4; nc++) {
    uint32_t hw[4], lw[4];
#pragma unroll
    for (int jj = 0; jj < 4; jj++) {
      float a  = xs[nc*8 + jj*2    ][tid];
      float bv = xs[nc*8 + jj*2 + 1][tid];
      uint32_t ab = __float_as_uint(a)  & 0xFFFF0000u;
      uint32_t bb = __float_as_uint(bv) & 0xFFFF0000u;
      hw[jj] = (ab >> 16) | bb;
      float alo = a  - __uint_as_float(ab);
      float blo = bv - __uint_as_float(bb);
      lw[jj] = (uint32_t)bf16_rne(alo) | ((uint32_t)bf16_rne(blo) << 16);
    }
    size_t toff = ((size_t)(b*64 + nt))*16384 + ((size_t)nc*256 + tid)*16;
    *(uint4*)(xtbuf + toff)           = make_uint4(hw[0], hw[1], hw[2], hw[3]);
    *(uint4*)(xtbuf + XT_HALF + toff) = make_uint4(lw[0], lw[1], lw[2], lw[3]);
  }
}

// ---------------------------------------------------------------------------
// K3: Z[n] = rowmax_m(e) + ln(rowsum exp); lane-local online stats over m.
__global__ __launch_bounds__(256) void k3_stats(char* __restrict__ ws) {
  int b = blockIdx.x >> 4, nb = blockIdx.x & 15;
  int tid = threadIdx.x, wave = tid >> 6, l = tid & 63;
  int lo5 = l & 31, hi5 = l >> 5;
  int n = nb*128 + wave*32 + lo5;

  short8 qhf[4], qlf[4];
  size_t qoff = ((size_t)b*N_ + n)*K_;
#pragma unroll
  for (int cs = 0; cs < 4; cs++) {
    qhf[cs] = *(const short8*)(ws + WSB_QH + (qoff + cs*16 + hi5*8)*2);
    qlf[cs] = *(const short8*)(ws + WSB_QL + (qoff + cs*16 + hi5*8)*2);
  }
  float M = -3.0e38f, S = 0.f;
  for (int mt = 0; mt < 64; mt++) {
    size_t koff = ((size_t)b*N_ + mt*32 + lo5)*K_;
    short8 khf[4], klf[4];
#pragma unroll
    for (int cs = 0; cs < 4; cs++) {
      khf[cs] = *(const short8*)(ws + WSB_KH + (koff + cs*16 + hi5*8)*2);
      klf[cs] = *(const short8*)(ws + WSB_KL + (koff + cs*16 + hi5*8)*2);
    }
    f32x16 E = {0.f};
#pragma unroll
    for (int cs = 0; cs < 4; cs++) {
      E = MFMA32(khf[cs], qhf[cs], E);
      E = MFMA32(khf[cs], qlf[cs], E);
      E = MFMA32(klf[cs], qhf[cs], E);
    }
    float tmax = E[0];
#pragma unroll
    for (int r = 1; r < 16; r++) tmax = fmaxf(tmax, E[r]);
    float nM = fmaxf(M, tmax);
    float sc = __expf(M - nM);
    float ss = 0.f;
#pragma unroll
    for (int r = 0; r < 16; r++) ss += __expf(E[r] - nM);
    S = fmaf(S, sc, ss);
    M = nM;
  }
  float Mo = __shfl_xor(M, 32, 64);
  float So = __shfl_xor(S, 32, 64);
  float Mg = fmaxf(M, Mo);
  float Sg = S*__expf(M - Mg) + So*__expf(Mo - Mg);
  if (hi5 == 0)
    ((float*)(ws + WSB_Z))[(size_t)b*N_ + n] = Mg + __logf(Sg);
}

// ---------------------------------------------------------------------------
// K4: O[m,c] = sum_n P[n,m]*x[n,c] (double-buffered staging), then fused
// epilogue: d = x - O*ics -> split bf16 -> swizzled LDS -> MFMA vs WtBF ->
// BN+ReLU+residual -> out. One barrier per n-tile.
__global__ __launch_bounds__(256, 2) void k4_ov(const float* __restrict__ x,
                                                char* __restrict__ ws,
                                                float* __restrict__ out) {
  __shared__ __align__(16) char xtile[65536];   // [buf 2][hi 16K | lo 16K]
  __shared__ float zsb[2][32];
  __shared__ float csL[64];
  int b = blockIdx.x >> 5, mblk = blockIdx.x & 31;
  int m0 = mblk*64;
  int tid = threadIdx.x, wave = tid >> 6, l = tid & 63;
  int lo5 = l & 31, hi5 = l >> 5;
  int msub = wave >> 1, c0 = (wave & 1)*128;
  int mg = m0 + msub*32 + lo5;
  const float* Zp = (const float*)(ws + WSB_Z);
  const char* XTH = ws + WSB_XT;
  const char* XTL = ws + WSB_XT + XT_HALF;

  short8 khf[4], klf[4];                      // loop-invariant B-frags (cols m)
  size_t koff = ((size_t)b*N_ + mg)*K_;
#pragma unroll
  for (int cs = 0; cs < 4; cs++) {
    khf[cs] = *(const short8*)(ws + WSB_KH + (koff + cs*16 + hi5*8)*2);
    klf[cs] = *(const short8*)(ws + WSB_KL + (koff + cs*16 + hi5*8)*2);
  }
  f32x16 accO[4];
#pragma unroll
  for (int ct = 0; ct < 4; ct++) accO[ct] = (f32x16){0.f};
  float csum = 0.f;

  auto STAGE = [&](int nt, int buf) {
    size_t src = (size_t)(b*64 + nt)*16384 + (size_t)tid*16;
    char* dst = xtile + buf*32768 + tid*16;
#pragma unroll
    for (int i = 0; i < 4; i++) GLOAD_LDS16(XTH + src + (size_t)i*4096, dst + i*4096);
#pragma unroll
    for (int i = 0; i < 4; i++) GLOAD_LDS16(XTL + src + (size_t)i*4096, dst + 16384 + i*4096);
    if (tid < 32) zsb[buf][tid] = Zp[(size_t)b*N_ + nt*32 + tid];
  };
  auto QLOAD = [&](int nt, short8* qh8, short8* ql8) {
    size_t qoff2 = ((size_t)b*N_ + nt*32 + lo5)*K_;
#pragma unroll
    for (int cs = 0; cs < 4; cs++) {
      qh8[cs] = *(const short8*)(ws + WSB_QH + (qoff2 + cs*16 + hi5*8)*2);
      ql8[cs] = *(const short8*)(ws + WSB_QL + (qoff2 + cs*16 + hi5*8)*2);
    }
  };
  auto COMPUTE = [&](int buf, const short8* qh8, const short8* ql8) {
    f32x16 E = {0.f};
#pragma unroll
    for (int cs = 0; cs < 4; cs++) {
      E = MFMA32(qh8[cs], khf[cs], E);
      E = MFMA32(qh8[cs], klf[cs], E);
      E = MFMA32(ql8[cs], khf[cs], E);
    }
    float ph[16], pl[16];
#pragma unroll
    for (int r = 0; r < 16; r++) {
      int nr = (r & 3) + 8*(r >> 2) + 4*hi5;
      float p = __expf(E[r] - zsb[buf][nr]);
      csum += p;
      uint32_t pb = __float_as_uint(p) & 0xFFFF0000u;
      ph[r] = __uint_as_float(pb);
      pl[r] = p - ph[r];
    }
    uint32_t Wh[8], Wl[8];
#pragma unroll
    for (int i = 0; i < 8; i++) {
      Wh[i] = (__float_as_uint(ph[2*i]) >> 16) | (__float_as_uint(ph[2*i+1]) & 0xFFFF0000u);
      uint32_t w;
      asm("v_cvt_pk_bf16_f32 %0, %1, %2" : "=v"(w) : "v"(pl[2*i]), "v"(pl[2*i+1]));
      Wl[i] = w;
    }
    short8 pha[2], pla[2];
#pragma unroll
    for (int s = 0; s < 2; s++) {
      uint32_t a0 = Wh[s*4+0], b0 = Wh[s*4+2];
      uint32_t a1 = Wh[s*4+1], b1 = Wh[s*4+3];
      asm("v_permlane32_swap_b32 %0, %1" : "+v"(a0), "+v"(b0));
      asm("v_permlane32_swap_b32 %0, %1" : "+v"(a1), "+v"(b1));
      union { uint32_t w[4]; short8 s8; } uh;
      uh.w[0] = a0; uh.w[1] = a1; uh.w[2] = b0; uh.w[3] = b1;
      pha[s] = uh.s8;
      uint32_t c0w = Wl[s*4+0], d0 = Wl[s*4+2];
      uint32_t c1w = Wl[s*4+1], d1 = Wl[s*4+3];
      asm("v_permlane32_swap_b32 %0, %1" : "+v"(c0w), "+v"(d0));
      asm("v_permlane32_swap_b32 %0, %1" : "+v"(c1w), "+v"(d1));
      union { uint32_t w[4]; short8 s8; } ul;
      ul.w[0] = c0w; ul.w[1] = c1w; ul.w[2] = d0; ul.w[3] = d1;
      pla[s] = ul.s8;
    }
    const char* xb = xtile + buf*32768;
#pragma unroll
    for (int ct = 0; ct < 4; ct++) {
      int cc = c0 + ct*32 + lo5;
      short8 bh[2], bl[2];
#pragma unroll
      for (int ns = 0; ns < 2; ns++) {
        size_t off = ((size_t)((ns*2 + hi5)*256 + cc))*16;
        bh[ns] = *(const short8*)(xb + off);
        bl[ns] = *(const short8*)(xb + 16384 + off);
      }
#pragma unroll
      for (int ns = 0; ns < 2; ns++) {
        accO[ct] = MFMA32(pha[ns], bh[ns], accO[ct]);
        accO[ct] = MFMA32(pha[ns], bl[ns], accO[ct]);
        accO[ct] = MFMA32(pla[ns], bh[ns], accO[ct]);
      }
    }
  };

  short8 qA[4], qlA[4], qB[4], qlB[4];
  STAGE(0, 0); QLOAD(0, qA, qlA);
  __syncthreads();
  for (int base = 0; base < 64; base += 2) {
    STAGE(base + 1, 1); QLOAD(base + 1, qB, qlB);
    COMPUTE(0, qA, qlA);
    __syncthreads();
    if (base + 2 < 64) { STAGE(base + 2, 0); QLOAD(base + 2, qA, qlA); }
    COMPUTE(1, qB, qlB);
    __syncthreads();
  }

  // ---- fused epilogue: d-split -> LDS -> MFMA vs WtBF -> BN/ReLU/residual
  csum += __shfl_xor(csum, 32, 64);
  if ((wave & 1) == 0 && hi5 == 0) csL[msub*32 + lo5] = csum;
  __syncthreads();
  // d = x - O*ics; split bf16; store swizzled: byte(m,c) = m*512 + ((c>>3 ^ (m&31))<<4) + (c&7)*2
#pragma unroll
  for (int r = 0; r < 16; r++) {
    int mloc = msub*32 + (r & 3) + 8*(r >> 2) + 4*hi5;
    float ics = 1.0f / (1e-6f + csL[mloc]);
#pragma unroll
    for (int ct = 0; ct < 4; ct++) {
      int cc = c0 + ct*32 + lo5;
      float xv = x[((size_t)b*N_ + m0 + mloc)*C_ + cc];
      float dv = fmaf(-accO[ct][r], ics, xv);
      uint32_t db = __float_as_uint(dv) & 0xFFFF0000u;
      int byte = mloc*512 + ((((cc >> 3) ^ (mloc & 31)) << 4)) + ((cc & 7) << 1);
      *(unsigned short*)(xtile + byte)         = (unsigned short)(db >> 16);
      *(unsigned short*)(xtile + 32768 + byte) = bf16_rne(dv - __uint_as_float(db));
    }
  }
  __syncthreads();
  // GEMM: out-tile rows m (64), cols o (256); wave w -> o-strip w*64.
  f32x16 accT[2][2];
#pragma unroll
  for (int ms = 0; ms < 2; ms++)
#pragma unroll
    for (int ot = 0; ot < 2; ot++) accT[ms][ot] = (f32x16){0.f};
#pragma unroll
  for (int cs = 0; cs < 16; cs++) {
    short8 ah[2], al[2], bh[2], bl[2];
#pragma unroll
    for (int ms = 0; ms < 2; ms++) {
      int off = (ms*32 + lo5)*512 + ((((cs*2 + hi5) ^ lo5)) << 4);
      ah[ms] = *(const short8*)(xtile + off);
      al[ms] = *(const short8*)(xtile + 32768 + off);
    }
#pragma unroll
    for (int ot = 0; ot < 2; ot++) {
      size_t wo = ((size_t)((wave*2 + ot)*32 + lo5)*C_ + cs*16 + hi5*8)*2;
      bh[ot] = *(const short8*)(ws + WSB_WBH + wo);
      bl[ot] = *(const short8*)(ws + WSB_WBL + wo);
    }
#pragma unroll
    for (int ms = 0; ms < 2; ms++)
#pragma unroll
      for (int ot = 0; ot < 2; ot++) {
        accT[ms][ot] = MFMA32(ah[ms], bh[ot], accT[ms][ot]);
        accT[ms][ot] = MFMA32(ah[ms], bl[ot], accT[ms][ot]);
        accT[ms][ot] = MFMA32(al[ms], bh[ot], accT[ms][ot]);
      }
  }
  const float* Sp = (const float*)(ws + WSB_S);
  const float* Cp = (const float*)(ws + WSB_CB);
  float sv[2], cv[2];
#pragma unroll
  for (int ot = 0; ot < 2; ot++) {
    int o = (wave*2 + ot)*32 + lo5;
    sv[ot] = Sp[o]; cv[ot] = Cp[o];
  }
#pragma unroll
  for (int ms = 0; ms < 2; ms++)
#pragma unroll
    for (int ot = 0; ot < 2; ot++)
#pragma unroll
      for (int r = 0; r < 16; r++) {
        int mloc = ms*32 + (r & 3) + 8*(r >> 2) + 4*hi5;
        int o = (wave*2 + ot)*32 + lo5;
        float bn = fmaf(sv[ot], accT[ms][ot][r], cv[ot]);
        bn = bn > 0.f ? bn : 0.f;
        size_t idx = ((size_t)b*N_ + m0 + mloc)*C_ + o;
        out[idx] = x[idx] + bn;
      }
}

// ---------------------------------------------------------------------------
extern "C" void kernel_launch(void* const* d_in, const int* in_sizes, int n_in,
                              void* d_out, int out_size, void* d_ws, size_t ws_size,
                              hipStream_t stream) {
  (void)in_sizes; (void)n_in; (void)out_size; (void)ws_size;
  const float* x     = (const float*)d_in[0];
  const float* Wq    = (const float*)d_in[1];
  const float* Wk    = (const float*)d_in[2];
  // d_in[3] (Wv) / d_in[4] (bv): dead in reference forward.
  const float* Wt    = (const float*)d_in[5];
  const float* bt    = (const float*)d_in[6];
  const float* gamma = (const float*)d_in[7];
  const float* beta  = (const float*)d_in[8];
  const float* mean  = (const float*)d_in[9];
  const float* var   = (const float*)d_in[10];
  char* ws = (char*)d_ws;
  float* out = (float*)d_out;

  k0_prep <<<C_,     C_,  0, stream>>>(Wq, Wk, Wt, bt, gamma, beta, mean, var, ws);
  k1_qk   <<<B_*64,  256, 0, stream>>>(x, ws, ws + WSB_XT);
  k3_stats<<<B_*16,  256, 0, stream>>>(ws);
  k4_ov   <<<B_*32,  256, 0, stream>>>(x, ws, out);
}